// Round 4
// baseline (523.758 us; speedup 1.0000x reference)
//
#include <hip/hip_runtime.h>
#include <hip/hip_bf16.h>
#include <stdint.h>

// ---------------------------------------------------------------------------
// wannModel: x0 = x@Ws^T + bs;  h_{l+1} = relu(h_l@W_l^T + b_l) + x0 (32x);
//            out = softmax(h@Wo^T + bo)  over 64 classes.
//
// Transposed-orientation MFMA chain (out^T = W * h^T): C/D layout (col=lane&15
// = batch) is lane-compatible with the next layer's B-operand layout. k-index
// mismatch absorbed by pre-permuting weights' k axis with
// pi(8q+j+32kt) = 4q+(j&3)+16*(j>>2)+32kt in a prep kernel. h stays in
// registers across all 32 layers; LDS holds only the 2x32KB weight dbuf.
//
// R4: back to R2's in-place tq dataflow (R3's hA/hB ping-pong pushed live
// state to ~230 VGPRs -> 130 MB scratch spill, FETCH/WRITE counters doubled),
// keeping R3's wins: hw v_cvt_pk_bf16_f32 pack, bias as the kt=0 MFMA C
// operand (no acc-init movs), f32x4 packed epilogue, 2x-unrolled dbuf loop.
// Peak live: x0f(64) + hfr(64) + tq(48 transient) + acc(32) -- fits 256.
// ---------------------------------------------------------------------------

typedef short bs8 __attribute__((ext_vector_type(8)));   // 8 x bf16 bits
typedef float f32x4 __attribute__((ext_vector_type(4)));

union Frag { bs8 v; uint32_t u[4]; };
union F4   { float4 f; f32x4 v; };

__device__ __forceinline__ uint32_t cvtpk(float lo, float hi) {
#if __has_builtin(__builtin_amdgcn_cvt_pk_bf16_f32)
  auto r = __builtin_amdgcn_cvt_pk_bf16_f32(lo, hi);   // dst.lo=cvt(lo)
  uint32_t u; __builtin_memcpy(&u, &r, 4);
  return u;
#else
  union { float f; uint32_t u; } a, b; a.f = lo; b.f = hi;
  uint32_t ra = a.u + 0x7fffu + ((a.u >> 16) & 1u);    // RNE, no NaN check
  uint32_t rb = b.u + 0x7fffu + ((b.u >> 16) & 1u);
  return (ra >> 16) | (rb & 0xffff0000u);
#endif
}

// ---------------------------------------------------------------------------
// Preprocess: bf16 weight fragments in d_ws. uint16 layout:
//   [0,16384)       W_start frags, NATURAL k order
//   [16384,540672)  32 chain layers, PI-permuted k
//   [540672,548864) W_out frags, PI-permuted k
// Element offset in region: ((nt*4+kt)*64 + lane)*8 + j.
// One thread per 8-element octet (68608 total), 16B stores.
// ---------------------------------------------------------------------------
__global__ void prep_frags(const float* __restrict__ w_start,
                           const float* __restrict__ masked_w,
                           const float* __restrict__ w_out,
                           uint16_t* __restrict__ dst) {
  int t = blockIdx.x * 256 + threadIdx.x;
  if (t >= 68608) return;
  int lane = t & 63, kt = (t >> 6) & 3, q = lane >> 4, m15 = lane & 15;
  float f[8];
  if (t < 2048) {                              // W_start (natural k)
    int nt = (t >> 8) & 7;
    const float* s = w_start + (nt * 16 + m15) * 128 + q * 8 + kt * 32;
    #pragma unroll
    for (int j = 0; j < 8; ++j) f[j] = s[j];
  } else if (t < 67584) {                      // chain (pi-permuted k)
    int t2 = t - 2048, l = t2 >> 11, nt = (t2 >> 8) & 7;
    const float* s = masked_w + ((l * 128) + nt * 16 + m15) * 128 + q * 4 + kt * 32;
    #pragma unroll
    for (int j = 0; j < 8; ++j) f[j] = s[(j & 3) + 16 * (j >> 2)];
  } else {                                     // W_out (pi-permuted k)
    int t3 = t - 67584, nt = (t3 >> 8) & 3;
    const float* s = w_out + (nt * 16 + m15) * 128 + q * 4 + kt * 32;
    #pragma unroll
    for (int j = 0; j < 8; ++j) f[j] = s[(j & 3) + 16 * (j >> 2)];
  }
  uint4 o;
  o.x = cvtpk(f[0], f[1]); o.y = cvtpk(f[2], f[3]);
  o.z = cvtpk(f[4], f[5]); o.w = cvtpk(f[6], f[7]);
  *reinterpret_cast<uint4*>(dst + t * 8) = o;
}

// ---------------------------------------------------------------------------
// Main kernel: 512 blocks x 256 threads (4 waves; wave owns 64 batch cols).
// LDS 64KB: bufA|bufB 32KB weight double-buffer, global_load_lds width-16.
// ---------------------------------------------------------------------------
extern __shared__ uint16_t lds[];

__global__ void __launch_bounds__(256, 2)
wann_main(const float* __restrict__ x,
          const float* __restrict__ b_start,
          const float* __restrict__ layer_b,
          const float* __restrict__ b_out,
          const uint16_t* __restrict__ wfrag,
          float* __restrict__ out) {
  const int tid  = threadIdx.x;
  const int lane = tid & 63;
  const int wave = tid >> 6;
  const int q    = lane >> 4;
  const int mc   = lane & 15;
  const long batch0 = (long)blockIdx.x * 256 + wave * 64;
  const f32x4 zero4 = {0.f, 0.f, 0.f, 0.f};

  uint16_t* bufA = lds;
  uint16_t* bufB = lds + 16384;

  auto stage_buf = [&](uint16_t* dstb, const uint16_t* srcb) {
    #pragma unroll
    for (int i = 0; i < 8; ++i) {
      __builtin_amdgcn_global_load_lds(
          (const __attribute__((address_space(1))) void*)(srcb + i * 2048 + wave * 512 + lane * 8),
          (__attribute__((address_space(3))) void*)(dstb + i * 2048 + wave * 512),
          16, 0, 0);
    }
  };

  stage_buf(bufA, wfrag);                    // W_start

  // ---- load x fragments (natural k: B[k=8q+j+32kt][batch=mc]) ----
  Frag xf[4][4];
  #pragma unroll
  for (int mt = 0; mt < 4; ++mt) {
    const float* xrow = x + (batch0 + mt * 16 + mc) * 128 + q * 8;
    #pragma unroll
    for (int kt = 0; kt < 4; ++kt) {
      float4 a = *reinterpret_cast<const float4*>(xrow + kt * 32);
      float4 b = *reinterpret_cast<const float4*>(xrow + kt * 32 + 4);
      xf[mt][kt].u[0] = cvtpk(a.x, a.y);
      xf[mt][kt].u[1] = cvtpk(a.z, a.w);
      xf[mt][kt].u[2] = cvtpk(b.x, b.y);
      xf[mt][kt].u[3] = cvtpk(b.z, b.w);
    }
  }

  __syncthreads();                           // W_start staged
  stage_buf(bufB, wfrag + 16384);            // layer 0, overlaps start matmul

  // ---- start layer: x0^T = Ws * x^T + bs (bias as kt=0 C operand) ----
  Frag x0f[4][4], hfr[4][4];
  #pragma unroll
  for (int p = 0; p < 4; ++p) {
    F4 bb[2];
    bb[0].f = *reinterpret_cast<const float4*>(b_start + (2 * p + 0) * 16 + q * 4);
    bb[1].f = *reinterpret_cast<const float4*>(b_start + (2 * p + 1) * 16 + q * 4);
    f32x4 acc[2][4];
    #pragma unroll
    for (int kt = 0; kt < 4; ++kt) {
      #pragma unroll
      for (int ntl = 0; ntl < 2; ++ntl) {
        const int nt = 2 * p + ntl;
        Frag wf;
        wf.v = *reinterpret_cast<const bs8*>(bufA + ((nt * 4 + kt) * 64 + lane) * 8);
        #pragma unroll
        for (int mt = 0; mt < 4; ++mt) {
          f32x4 c = (kt == 0) ? bb[ntl].v : acc[ntl][mt];
          acc[ntl][mt] = __builtin_amdgcn_mfma_f32_16x16x32_bf16(wf.v, xf[mt][kt].v, c, 0, 0, 0);
        }
      }
    }
    #pragma unroll
    for (int mt = 0; mt < 4; ++mt)
      #pragma unroll
      for (int ntl = 0; ntl < 2; ++ntl) {
        x0f[mt][p].u[2 * ntl + 0] = cvtpk(acc[ntl][mt][0], acc[ntl][mt][1]);
        x0f[mt][p].u[2 * ntl + 1] = cvtpk(acc[ntl][mt][2], acc[ntl][mt][3]);
      }
  }
  #pragma unroll
  for (int mt = 0; mt < 4; ++mt)
    #pragma unroll
    for (int kt = 0; kt < 4; ++kt)
      hfr[mt][kt].v = x0f[mt][kt].v;         // h = x0

  // ---- one chain layer, in place: hfr = bf16( relu(W hfr + b) + x0 ) ----
  // tq buffers passes 0..2 (their old frags are still MFMA inputs for later
  // passes); pass 3 writes hfr[.][3] directly (dead after pass-3 MFMAs).
  auto chain_layer = [&](const uint16_t* wl, const float* bl) {
    uint32_t tq[3][4][4];
    #pragma unroll
    for (int p = 0; p < 4; ++p) {
      F4 bb[2];
      bb[0].f = *reinterpret_cast<const float4*>(bl + (2 * p + 0) * 16 + q * 4);
      bb[1].f = *reinterpret_cast<const float4*>(bl + (2 * p + 1) * 16 + q * 4);
      f32x4 acc[2][4];
      #pragma unroll
      for (int kt = 0; kt < 4; ++kt) {
        #pragma unroll
        for (int ntl = 0; ntl < 2; ++ntl) {
          const int nt = 2 * p + ntl;
          Frag wf;
          wf.v = *reinterpret_cast<const bs8*>(wl + ((nt * 4 + kt) * 64 + lane) * 8);
          #pragma unroll
          for (int mt = 0; mt < 4; ++mt) {
            f32x4 c = (kt == 0) ? bb[ntl].v : acc[ntl][mt];
            acc[ntl][mt] = __builtin_amdgcn_mfma_f32_16x16x32_bf16(wf.v, hfr[mt][kt].v, c, 0, 0, 0);
          }
        }
      }
      #pragma unroll
      for (int mt = 0; mt < 4; ++mt) {
        #pragma unroll
        for (int ntl = 0; ntl < 2; ++ntl) {
          f32x4 r = __builtin_elementwise_max(acc[ntl][mt], zero4);
          uint32_t xw0 = x0f[mt][p].u[2 * ntl + 0];
          uint32_t xw1 = x0f[mt][p].u[2 * ntl + 1];
          f32x4 xv;
          xv[0] = __uint_as_float(xw0 << 16);
          xv[1] = __uint_as_float(xw0 & 0xffff0000u);
          xv[2] = __uint_as_float(xw1 << 16);
          xv[3] = __uint_as_float(xw1 & 0xffff0000u);
          r = r + xv;
          uint32_t pw0 = cvtpk(r[0], r[1]);
          uint32_t pw1 = cvtpk(r[2], r[3]);
          if (p < 3) {
            tq[p][mt][2 * ntl + 0] = pw0;
            tq[p][mt][2 * ntl + 1] = pw1;
          } else {
            hfr[mt][3].u[2 * ntl + 0] = pw0;
            hfr[mt][3].u[2 * ntl + 1] = pw1;
          }
        }
      }
    }
    #pragma unroll
    for (int mt = 0; mt < 4; ++mt)
      #pragma unroll
      for (int p = 0; p < 3; ++p)
        #pragma unroll
        for (int w = 0; w < 4; ++w)
          hfr[mt][p].u[w] = tq[p][mt][w];
  };

  // ---- 32-layer chain; 2x-unrolled double-buffer schedule ----
  const uint16_t* chain = wfrag + 16384;
  __syncthreads();                                   // layer 0 staged in bufB
  stage_buf(bufA, chain + 16384);                    // layer 1 (W_start dead)
  chain_layer(bufB, layer_b);                        // layer 0
  #pragma unroll 1
  for (int l = 1; l < 31; l += 2) {
    __syncthreads();
    stage_buf(bufB, chain + (l + 1) * 16384);
    chain_layer(bufA, layer_b + l * 128);            // odd layer
    __syncthreads();
    if (l + 2 < 32) stage_buf(bufA, chain + (l + 2) * 16384);
    chain_layer(bufB, layer_b + (l + 1) * 128);      // even layer
  }
  __syncthreads();
  chain_layer(bufA, layer_b + 31 * 128);             // layer 31

  // ---- output layer: logits^T = Wo * h^T + bo (W_out from global, L2) ----
  const uint16_t* wout = wfrag + 540672;
  F4 bo[4];
  #pragma unroll
  for (int nt = 0; nt < 4; ++nt)
    bo[nt].f = *reinterpret_cast<const float4*>(b_out + nt * 16 + q * 4);
  f32x4 ao[4][4];  // [nt][mt]
  #pragma unroll
  for (int kt = 0; kt < 4; ++kt) {
    #pragma unroll
    for (int nt = 0; nt < 4; ++nt) {
      Frag wf;
      wf.v = *reinterpret_cast<const bs8*>(wout + ((nt * 4 + kt) * 64 + lane) * 8);
      #pragma unroll
      for (int mt = 0; mt < 4; ++mt) {
        f32x4 c = (kt == 0) ? bo[nt].v : ao[nt][mt];
        ao[nt][mt] = __builtin_amdgcn_mfma_f32_16x16x32_bf16(wf.v, hfr[mt][kt].v, c, 0, 0, 0);
      }
    }
  }

  // ---- softmax over 64 classes + transposed store via LDS (bufB free) ----
  float* tr = reinterpret_cast<float*>(lds + 16384) + wave * 1088;
  #pragma unroll
  for (int mt = 0; mt < 4; ++mt) {
    float e[16];
    float M = -3.0e38f;
    #pragma unroll
    for (int nt = 0; nt < 4; ++nt)
      #pragma unroll
      for (int r = 0; r < 4; ++r)
        M = fmaxf(M, ao[nt][mt][r]);
    M = fmaxf(M, __shfl_xor(M, 16, 64));
    M = fmaxf(M, __shfl_xor(M, 32, 64));
    float S = 0.0f;
    #pragma unroll
    for (int nt = 0; nt < 4; ++nt)
      #pragma unroll
      for (int r = 0; r < 4; ++r) {
        float t = exp2f((ao[nt][mt][r] - M) * 1.4426950408889634f);
        e[nt * 4 + r] = t;
        S += t;
      }
    S += __shfl_xor(S, 16, 64);
    S += __shfl_xor(S, 32, 64);
    const float inv = 1.0f / S;
    #pragma unroll
    for (int nt = 0; nt < 4; ++nt) {
      float4 pv;
      pv.x = e[nt * 4 + 0] * inv;
      pv.y = e[nt * 4 + 1] * inv;
      pv.z = e[nt * 4 + 2] * inv;
      pv.w = e[nt * 4 + 3] * inv;
      *reinterpret_cast<float4*>(tr + mc * 68 + nt * 16 + q * 4) = pv;
    }
    __asm__ volatile("s_waitcnt lgkmcnt(0)" ::: "memory");
    #pragma unroll
    for (int it = 0; it < 4; ++it) {
      int row = it * 4 + (lane >> 4);
      float4 v = *reinterpret_cast<const float4*>(tr + row * 68 + (lane & 15) * 4);
      long gr = batch0 + mt * 16 + row;
      *reinterpret_cast<float4*>(out + gr * 64 + (lane & 15) * 4) = v;
    }
    __asm__ volatile("s_waitcnt lgkmcnt(0)" ::: "memory");
  }
}

// ---------------------------------------------------------------------------
extern "C" void kernel_launch(void* const* d_in, const int* in_sizes, int n_in,
                              void* d_out, int out_size, void* d_ws, size_t ws_size,
                              hipStream_t stream) {
  const float* x        = (const float*)d_in[0];
  const float* w_start  = (const float*)d_in[1];
  const float* b_start  = (const float*)d_in[2];
  const float* masked_w = (const float*)d_in[3];
  const float* layer_b  = (const float*)d_in[4];
  const float* w_out    = (const float*)d_in[5];
  const float* b_out    = (const float*)d_in[6];
  uint16_t* wfrag = (uint16_t*)d_ws;   // 1,097,728 B < ws_size

  prep_frags<<<268, 256, 0, stream>>>(w_start, masked_w, w_out, wfrag);
  wann_main<<<512, 256, 65536, stream>>>(x, b_start, layer_b, b_out, wfrag,
                                         (float*)d_out);
}

// Round 5
// 308.233 us; speedup vs baseline: 1.6992x; 1.6992x over previous
//
#include <hip/hip_runtime.h>
#include <hip/hip_bf16.h>
#include <stdint.h>

// ---------------------------------------------------------------------------
// wannModel: x0 = x@Ws^T + bs;  h_{l+1} = relu(h_l@W_l^T + b_l) + x0 (32x);
//            out = softmax(h@Wo^T + bo)  over 64 classes.
//
// Transposed-orientation MFMA chain (out^T = W * h^T): C/D layout (col=lane&15
// = batch) is lane-compatible with the next layer's B-operand layout. k-index
// mismatch absorbed by pre-permuting weights' k axis with
// pi(8q+j+32kt) = 4q+(j&3)+16*(j>>2)+32kt in a prep kernel. h stays in
// registers across all 32 layers; LDS holds only the 2x32KB weight dbuf.
//
// R5: mt=4 per wave sat exactly at the 256-reg unified-file cliff; R2/R3/R4
// showed allocator spill decisions flipping wildly (FETCH 47->112->582 MB).
// Fix is structural: each wave now owns 32 batch cols (mt=2), grid 1024.
// Live state ~130 regs -> no spill possible. Per-CU pipes: MFMA ~69us floor,
// LDS-read ~42us, VALU ~27us (hw cvt_pk_bf16). Keeps R3/R4 micro-opts.
// ---------------------------------------------------------------------------

typedef short bs8 __attribute__((ext_vector_type(8)));   // 8 x bf16 bits
typedef float f32x4 __attribute__((ext_vector_type(4)));

union Frag { bs8 v; uint32_t u[4]; };
union F4   { float4 f; f32x4 v; };

__device__ __forceinline__ uint32_t cvtpk(float lo, float hi) {
#if __has_builtin(__builtin_amdgcn_cvt_pk_bf16_f32)
  auto r = __builtin_amdgcn_cvt_pk_bf16_f32(lo, hi);   // dst.lo=cvt(lo)
  uint32_t u; __builtin_memcpy(&u, &r, 4);
  return u;
#else
  union { float f; uint32_t u; } a, b; a.f = lo; b.f = hi;
  uint32_t ra = a.u + 0x7fffu + ((a.u >> 16) & 1u);    // RNE, no NaN check
  uint32_t rb = b.u + 0x7fffu + ((b.u >> 16) & 1u);
  return (ra >> 16) | (rb & 0xffff0000u);
#endif
}

// ---------------------------------------------------------------------------
// Preprocess: bf16 weight fragments in d_ws. uint16 layout:
//   [0,16384)       W_start frags, NATURAL k order
//   [16384,540672)  32 chain layers, PI-permuted k
//   [540672,548864) W_out frags, PI-permuted k
// Element offset in region: ((nt*4+kt)*64 + lane)*8 + j.
// One thread per 8-element octet (68608 total), 16B stores.
// ---------------------------------------------------------------------------
__global__ void prep_frags(const float* __restrict__ w_start,
                           const float* __restrict__ masked_w,
                           const float* __restrict__ w_out,
                           uint16_t* __restrict__ dst) {
  int t = blockIdx.x * 256 + threadIdx.x;
  if (t >= 68608) return;
  int lane = t & 63, kt = (t >> 6) & 3, q = lane >> 4, m15 = lane & 15;
  float f[8];
  if (t < 2048) {                              // W_start (natural k)
    int nt = (t >> 8) & 7;
    const float* s = w_start + (nt * 16 + m15) * 128 + q * 8 + kt * 32;
    #pragma unroll
    for (int j = 0; j < 8; ++j) f[j] = s[j];
  } else if (t < 67584) {                      // chain (pi-permuted k)
    int t2 = t - 2048, l = t2 >> 11, nt = (t2 >> 8) & 7;
    const float* s = masked_w + ((l * 128) + nt * 16 + m15) * 128 + q * 4 + kt * 32;
    #pragma unroll
    for (int j = 0; j < 8; ++j) f[j] = s[(j & 3) + 16 * (j >> 2)];
  } else {                                     // W_out (pi-permuted k)
    int t3 = t - 67584, nt = (t3 >> 8) & 3;
    const float* s = w_out + (nt * 16 + m15) * 128 + q * 4 + kt * 32;
    #pragma unroll
    for (int j = 0; j < 8; ++j) f[j] = s[(j & 3) + 16 * (j >> 2)];
  }
  uint4 o;
  o.x = cvtpk(f[0], f[1]); o.y = cvtpk(f[2], f[3]);
  o.z = cvtpk(f[4], f[5]); o.w = cvtpk(f[6], f[7]);
  *reinterpret_cast<uint4*>(dst + t * 8) = o;
}

// ---------------------------------------------------------------------------
// Main kernel: 1024 blocks x 256 threads (4 waves; wave owns 32 batch cols
// = 2 m-tiles of 16). LDS 64KB: bufA|bufB 32KB weight double-buffer.
// ---------------------------------------------------------------------------
extern __shared__ uint16_t lds[];

__global__ void __launch_bounds__(256, 2)
wann_main(const float* __restrict__ x,
          const float* __restrict__ b_start,
          const float* __restrict__ layer_b,
          const float* __restrict__ b_out,
          const uint16_t* __restrict__ wfrag,
          float* __restrict__ out) {
  const int tid  = threadIdx.x;
  const int lane = tid & 63;
  const int wave = tid >> 6;
  const int q    = lane >> 4;
  const int mc   = lane & 15;
  const long batch0 = (long)blockIdx.x * 128 + wave * 32;
  const f32x4 zero4 = {0.f, 0.f, 0.f, 0.f};

  uint16_t* bufA = lds;
  uint16_t* bufB = lds + 16384;

  auto stage_buf = [&](uint16_t* dstb, const uint16_t* srcb) {
    #pragma unroll
    for (int i = 0; i < 8; ++i) {
      __builtin_amdgcn_global_load_lds(
          (const __attribute__((address_space(1))) void*)(srcb + i * 2048 + wave * 512 + lane * 8),
          (__attribute__((address_space(3))) void*)(dstb + i * 2048 + wave * 512),
          16, 0, 0);
    }
  };

  stage_buf(bufA, wfrag);                    // W_start

  // ---- load x fragments (natural k: B[k=8q+j+32kt][batch=mc]) ----
  Frag xf[2][4];
  #pragma unroll
  for (int mt = 0; mt < 2; ++mt) {
    const float* xrow = x + (batch0 + mt * 16 + mc) * 128 + q * 8;
    #pragma unroll
    for (int kt = 0; kt < 4; ++kt) {
      float4 a = *reinterpret_cast<const float4*>(xrow + kt * 32);
      float4 b = *reinterpret_cast<const float4*>(xrow + kt * 32 + 4);
      xf[mt][kt].u[0] = cvtpk(a.x, a.y);
      xf[mt][kt].u[1] = cvtpk(a.z, a.w);
      xf[mt][kt].u[2] = cvtpk(b.x, b.y);
      xf[mt][kt].u[3] = cvtpk(b.z, b.w);
    }
  }

  __syncthreads();                           // W_start staged
  stage_buf(bufB, wfrag + 16384);            // layer 0, overlaps start matmul

  // ---- start layer: x0^T = Ws * x^T + bs (bias as kt=0 C operand) ----
  Frag x0f[2][4], hfr[2][4];
  #pragma unroll
  for (int p = 0; p < 4; ++p) {
    F4 bb[2];
    bb[0].f = *reinterpret_cast<const float4*>(b_start + (2 * p + 0) * 16 + q * 4);
    bb[1].f = *reinterpret_cast<const float4*>(b_start + (2 * p + 1) * 16 + q * 4);
    f32x4 acc[2][2];
    #pragma unroll
    for (int kt = 0; kt < 4; ++kt) {
      #pragma unroll
      for (int ntl = 0; ntl < 2; ++ntl) {
        const int nt = 2 * p + ntl;
        Frag wf;
        wf.v = *reinterpret_cast<const bs8*>(bufA + ((nt * 4 + kt) * 64 + lane) * 8);
        #pragma unroll
        for (int mt = 0; mt < 2; ++mt) {
          f32x4 c = (kt == 0) ? bb[ntl].v : acc[ntl][mt];
          acc[ntl][mt] = __builtin_amdgcn_mfma_f32_16x16x32_bf16(wf.v, xf[mt][kt].v, c, 0, 0, 0);
        }
      }
    }
    #pragma unroll
    for (int mt = 0; mt < 2; ++mt)
      #pragma unroll
      for (int ntl = 0; ntl < 2; ++ntl) {
        x0f[mt][p].u[2 * ntl + 0] = cvtpk(acc[ntl][mt][0], acc[ntl][mt][1]);
        x0f[mt][p].u[2 * ntl + 1] = cvtpk(acc[ntl][mt][2], acc[ntl][mt][3]);
      }
  }
  #pragma unroll
  for (int mt = 0; mt < 2; ++mt)
    #pragma unroll
    for (int kt = 0; kt < 4; ++kt)
      hfr[mt][kt].v = x0f[mt][kt].v;         // h = x0

  // ---- one chain layer, in place: hfr = bf16( relu(W hfr + b) + x0 ) ----
  // tq buffers passes 0..2 (their old frags are still MFMA inputs for later
  // passes); pass 3 writes hfr[.][3] directly (dead after pass-3 MFMAs).
  auto chain_layer = [&](const uint16_t* wl, const float* bl) {
    uint32_t tq[3][2][4];
    #pragma unroll
    for (int p = 0; p < 4; ++p) {
      F4 bb[2];
      bb[0].f = *reinterpret_cast<const float4*>(bl + (2 * p + 0) * 16 + q * 4);
      bb[1].f = *reinterpret_cast<const float4*>(bl + (2 * p + 1) * 16 + q * 4);
      f32x4 acc[2][2];
      #pragma unroll
      for (int kt = 0; kt < 4; ++kt) {
        #pragma unroll
        for (int ntl = 0; ntl < 2; ++ntl) {
          const int nt = 2 * p + ntl;
          Frag wf;
          wf.v = *reinterpret_cast<const bs8*>(wl + ((nt * 4 + kt) * 64 + lane) * 8);
          #pragma unroll
          for (int mt = 0; mt < 2; ++mt) {
            f32x4 c = (kt == 0) ? bb[ntl].v : acc[ntl][mt];
            acc[ntl][mt] = __builtin_amdgcn_mfma_f32_16x16x32_bf16(wf.v, hfr[mt][kt].v, c, 0, 0, 0);
          }
        }
      }
      #pragma unroll
      for (int mt = 0; mt < 2; ++mt) {
        #pragma unroll
        for (int ntl = 0; ntl < 2; ++ntl) {
          f32x4 r = __builtin_elementwise_max(acc[ntl][mt], zero4);
          uint32_t xw0 = x0f[mt][p].u[2 * ntl + 0];
          uint32_t xw1 = x0f[mt][p].u[2 * ntl + 1];
          f32x4 xv;
          xv[0] = __uint_as_float(xw0 << 16);
          xv[1] = __uint_as_float(xw0 & 0xffff0000u);
          xv[2] = __uint_as_float(xw1 << 16);
          xv[3] = __uint_as_float(xw1 & 0xffff0000u);
          r = r + xv;
          uint32_t pw0 = cvtpk(r[0], r[1]);
          uint32_t pw1 = cvtpk(r[2], r[3]);
          if (p < 3) {
            tq[p][mt][2 * ntl + 0] = pw0;
            tq[p][mt][2 * ntl + 1] = pw1;
          } else {
            hfr[mt][3].u[2 * ntl + 0] = pw0;
            hfr[mt][3].u[2 * ntl + 1] = pw1;
          }
        }
      }
    }
    #pragma unroll
    for (int mt = 0; mt < 2; ++mt)
      #pragma unroll
      for (int p = 0; p < 3; ++p)
        #pragma unroll
        for (int w = 0; w < 4; ++w)
          hfr[mt][p].u[w] = tq[p][mt][w];
  };

  // ---- 32-layer chain; 2x-unrolled double-buffer schedule ----
  const uint16_t* chain = wfrag + 16384;
  __syncthreads();                                   // layer 0 staged in bufB
  stage_buf(bufA, chain + 16384);                    // layer 1 (W_start dead)
  chain_layer(bufB, layer_b);                        // layer 0
  #pragma unroll 1
  for (int l = 1; l < 31; l += 2) {
    __syncthreads();
    stage_buf(bufB, chain + (l + 1) * 16384);
    chain_layer(bufA, layer_b + l * 128);            // odd layer
    __syncthreads();
    if (l + 2 < 32) stage_buf(bufA, chain + (l + 2) * 16384);
    chain_layer(bufB, layer_b + (l + 1) * 128);      // even layer
  }
  __syncthreads();
  chain_layer(bufA, layer_b + 31 * 128);             // layer 31

  // ---- output layer: logits^T = Wo * h^T + bo (W_out from global, L2) ----
  const uint16_t* wout = wfrag + 540672;
  F4 bo[4];
  #pragma unroll
  for (int nt = 0; nt < 4; ++nt)
    bo[nt].f = *reinterpret_cast<const float4*>(b_out + nt * 16 + q * 4);
  f32x4 ao[4][2];  // [nt][mt]
  #pragma unroll
  for (int kt = 0; kt < 4; ++kt) {
    #pragma unroll
    for (int nt = 0; nt < 4; ++nt) {
      Frag wf;
      wf.v = *reinterpret_cast<const bs8*>(wout + ((nt * 4 + kt) * 64 + lane) * 8);
      #pragma unroll
      for (int mt = 0; mt < 2; ++mt) {
        f32x4 c = (kt == 0) ? bo[nt].v : ao[nt][mt];
        ao[nt][mt] = __builtin_amdgcn_mfma_f32_16x16x32_bf16(wf.v, hfr[mt][kt].v, c, 0, 0, 0);
      }
    }
  }

  // ---- softmax over 64 classes + transposed store via LDS (bufB free) ----
  float* tr = reinterpret_cast<float*>(lds + 16384) + wave * 1088;
  #pragma unroll
  for (int mt = 0; mt < 2; ++mt) {
    float e[16];
    float M = -3.0e38f;
    #pragma unroll
    for (int nt = 0; nt < 4; ++nt)
      #pragma unroll
      for (int r = 0; r < 4; ++r)
        M = fmaxf(M, ao[nt][mt][r]);
    M = fmaxf(M, __shfl_xor(M, 16, 64));
    M = fmaxf(M, __shfl_xor(M, 32, 64));
    float S = 0.0f;
    #pragma unroll
    for (int nt = 0; nt < 4; ++nt)
      #pragma unroll
      for (int r = 0; r < 4; ++r) {
        float t = exp2f((ao[nt][mt][r] - M) * 1.4426950408889634f);
        e[nt * 4 + r] = t;
        S += t;
      }
    S += __shfl_xor(S, 16, 64);
    S += __shfl_xor(S, 32, 64);
    const float inv = 1.0f / S;
    #pragma unroll
    for (int nt = 0; nt < 4; ++nt) {
      float4 pv;
      pv.x = e[nt * 4 + 0] * inv;
      pv.y = e[nt * 4 + 1] * inv;
      pv.z = e[nt * 4 + 2] * inv;
      pv.w = e[nt * 4 + 3] * inv;
      *reinterpret_cast<float4*>(tr + mc * 68 + nt * 16 + q * 4) = pv;
    }
    __asm__ volatile("s_waitcnt lgkmcnt(0)" ::: "memory");
    #pragma unroll
    for (int it = 0; it < 4; ++it) {
      int row = it * 4 + (lane >> 4);
      float4 v = *reinterpret_cast<const float4*>(tr + row * 68 + (lane & 15) * 4);
      long gr = batch0 + mt * 16 + row;
      *reinterpret_cast<float4*>(out + gr * 64 + (lane & 15) * 4) = v;
    }
    __asm__ volatile("s_waitcnt lgkmcnt(0)" ::: "memory");
  }
}

// ---------------------------------------------------------------------------
extern "C" void kernel_launch(void* const* d_in, const int* in_sizes, int n_in,
                              void* d_out, int out_size, void* d_ws, size_t ws_size,
                              hipStream_t stream) {
  const float* x        = (const float*)d_in[0];
  const float* w_start  = (const float*)d_in[1];
  const float* b_start  = (const float*)d_in[2];
  const float* masked_w = (const float*)d_in[3];
  const float* layer_b  = (const float*)d_in[4];
  const float* w_out    = (const float*)d_in[5];
  const float* b_out    = (const float*)d_in[6];
  uint16_t* wfrag = (uint16_t*)d_ws;   // 1,097,728 B < ws_size

  prep_frags<<<268, 256, 0, stream>>>(w_start, masked_w, w_out, wfrag);
  wann_main<<<1024, 256, 65536, stream>>>(x, b_start, layer_b, b_out, wfrag,
                                          (float*)d_out);
}

// Round 6
// 285.293 us; speedup vs baseline: 1.8359x; 1.0804x over previous
//
#include <hip/hip_runtime.h>
#include <hip/hip_bf16.h>
#include <stdint.h>

// ---------------------------------------------------------------------------
// wannModel: x0 = x@Ws^T + bs;  h_{l+1} = relu(h_l@W_l^T + b_l) + x0 (32x);
//            out = softmax(h@Wo^T + bo)  over 64 classes.
//
// Transposed-orientation MFMA chain (out^T = W * h^T): C/D layout (col=lane&15
// = batch) is lane-compatible with the next layer's B-operand layout. k-index
// mismatch absorbed by pre-permuting weights' k axis with
// pi(8q+j+32kt) = 4q+(j&3)+16*(j>>2)+32kt in a prep kernel. h stays in
// registers across all 32 layers.
//
// R6: R5 showed 2 blocks/CU lockstep (Occ 22%, Mfma 25%, VALU 43% serialized
// by per-block barriers). Fix: 16KB half-layer chunk double-buffer -> LDS
// 32KB/block -> 3 blocks/CU (launch_bounds(256,3)); independent blocks cover
// each other's barrier/epilogue phases. Per-CU pipe balance at 12 waves/CU:
// MFMA ~5.0k cy/layer, LDS-read ~5.8k, VALU overlapped. Also: all-8 bias
// loads hoisted per layer (kills 3 VMEM serialization points), h ping-pong
// (hA/hB; fits regs at mt=2, unlike R3's mt=4 spill).
// ---------------------------------------------------------------------------

typedef short bs8 __attribute__((ext_vector_type(8)));   // 8 x bf16 bits
typedef float f32x4 __attribute__((ext_vector_type(4)));

union Frag { bs8 v; uint32_t u[4]; };
union F4   { float4 f; f32x4 v; };

__device__ __forceinline__ uint32_t cvtpk(float lo, float hi) {
#if __has_builtin(__builtin_amdgcn_cvt_pk_bf16_f32)
  auto r = __builtin_amdgcn_cvt_pk_bf16_f32(lo, hi);   // dst.lo=cvt(lo)
  uint32_t u; __builtin_memcpy(&u, &r, 4);
  return u;
#else
  union { float f; uint32_t u; } a, b; a.f = lo; b.f = hi;
  uint32_t ra = a.u + 0x7fffu + ((a.u >> 16) & 1u);    // RNE, no NaN check
  uint32_t rb = b.u + 0x7fffu + ((b.u >> 16) & 1u);
  return (ra >> 16) | (rb & 0xffff0000u);
#endif
}

// ---------------------------------------------------------------------------
// Preprocess: bf16 weight fragments in d_ws. uint16 layout:
//   [0,16384)       W_start frags, NATURAL k order
//   [16384,540672)  32 chain layers, PI-permuted k
//   [540672,548864) W_out frags, PI-permuted k
// Element offset in region: ((nt*4+kt)*64 + lane)*8 + j.
// Half-layer chunk c of a layer = nt in [4c,4c+4) = 8192 contiguous elements.
// ---------------------------------------------------------------------------
__global__ void prep_frags(const float* __restrict__ w_start,
                           const float* __restrict__ masked_w,
                           const float* __restrict__ w_out,
                           uint16_t* __restrict__ dst) {
  int t = blockIdx.x * 256 + threadIdx.x;
  if (t >= 68608) return;
  int lane = t & 63, kt = (t >> 6) & 3, q = lane >> 4, m15 = lane & 15;
  float f[8];
  if (t < 2048) {                              // W_start (natural k)
    int nt = (t >> 8) & 7;
    const float* s = w_start + (nt * 16 + m15) * 128 + q * 8 + kt * 32;
    #pragma unroll
    for (int j = 0; j < 8; ++j) f[j] = s[j];
  } else if (t < 67584) {                      // chain (pi-permuted k)
    int t2 = t - 2048, l = t2 >> 11, nt = (t2 >> 8) & 7;
    const float* s = masked_w + ((l * 128) + nt * 16 + m15) * 128 + q * 4 + kt * 32;
    #pragma unroll
    for (int j = 0; j < 8; ++j) f[j] = s[(j & 3) + 16 * (j >> 2)];
  } else {                                     // W_out (pi-permuted k)
    int t3 = t - 67584, nt = (t3 >> 8) & 3;
    const float* s = w_out + (nt * 16 + m15) * 128 + q * 4 + kt * 32;
    #pragma unroll
    for (int j = 0; j < 8; ++j) f[j] = s[(j & 3) + 16 * (j >> 2)];
  }
  uint4 o;
  o.x = cvtpk(f[0], f[1]); o.y = cvtpk(f[2], f[3]);
  o.z = cvtpk(f[4], f[5]); o.w = cvtpk(f[6], f[7]);
  *reinterpret_cast<uint4*>(dst + t * 8) = o;
}

// ---------------------------------------------------------------------------
// Main kernel: 1024 blocks x 256 threads (4 waves; wave owns 32 batch cols
// = 2 m-tiles of 16). LDS 32KB: X|Y 16KB half-layer chunk double-buffer.
// Chunk stream: Wsc0, Wsc1, L0c0, L0c1, ..., L31c1; even chunks -> X,
// odd -> Y. Passes 0,1 of every layer read X; passes 2,3 read Y.
// ---------------------------------------------------------------------------
extern __shared__ uint16_t lds[];

__global__ void __launch_bounds__(256, 3)
wann_main(const float* __restrict__ x,
          const float* __restrict__ b_start,
          const float* __restrict__ layer_b,
          const float* __restrict__ b_out,
          const uint16_t* __restrict__ wfrag,
          float* __restrict__ out) {
  const int tid  = threadIdx.x;
  const int lane = tid & 63;
  const int wave = tid >> 6;
  const int q    = lane >> 4;
  const int mc   = lane & 15;
  const long batch0 = (long)blockIdx.x * 128 + wave * 32;
  const f32x4 zero4 = {0.f, 0.f, 0.f, 0.f};

  uint16_t* X = lds;
  uint16_t* Y = lds + 8192;

  // stage one 16KB chunk (4 x width-16 global_load_lds per wave)
  auto stage = [&](uint16_t* dstb, const uint16_t* srcb) {
    #pragma unroll
    for (int i = 0; i < 4; ++i) {
      __builtin_amdgcn_global_load_lds(
          (const __attribute__((address_space(1))) void*)(srcb + i * 2048 + wave * 512 + lane * 8),
          (__attribute__((address_space(3))) void*)(dstb + i * 2048 + wave * 512),
          16, 0, 0);
    }
  };

  stage(X, wfrag);                           // W_start chunk0

  // ---- load x fragments (natural k: B[k=8q+j+32kt][batch=mc]) ----
  Frag xf[2][4];
  #pragma unroll
  for (int mt = 0; mt < 2; ++mt) {
    const float* xrow = x + (batch0 + mt * 16 + mc) * 128 + q * 8;
    #pragma unroll
    for (int kt = 0; kt < 4; ++kt) {
      float4 a = *reinterpret_cast<const float4*>(xrow + kt * 32);
      float4 b = *reinterpret_cast<const float4*>(xrow + kt * 32 + 4);
      xf[mt][kt].u[0] = cvtpk(a.x, a.y);
      xf[mt][kt].u[1] = cvtpk(a.z, a.w);
      xf[mt][kt].u[2] = cvtpk(b.x, b.y);
      xf[mt][kt].u[3] = cvtpk(b.z, b.w);
    }
  }

  Frag x0f[2][4], hA[2][4], hB[2][4];

  // ---- start layer half: 2 passes from `buf`, input xf, bias-only epilogue
  auto start_half = [&](const uint16_t* buf, int p0, const F4* bb) {
    #pragma unroll
    for (int pp = 0; pp < 2; ++pp) {
      const int p = p0 + pp;
      f32x4 acc[2][2];
      #pragma unroll
      for (int kt = 0; kt < 4; ++kt)
        #pragma unroll
        for (int ntl = 0; ntl < 2; ++ntl) {
          const int ntloc = 2 * pp + ntl;           // nt within chunk
          Frag wf;
          wf.v = *reinterpret_cast<const bs8*>(buf + ((ntloc * 4 + kt) * 64 + lane) * 8);
          #pragma unroll
          for (int mt = 0; mt < 2; ++mt) {
            f32x4 c = (kt == 0) ? bb[2 * p + ntl].v : acc[ntl][mt];
            acc[ntl][mt] = __builtin_amdgcn_mfma_f32_16x16x32_bf16(wf.v, xf[mt][kt].v, c, 0, 0, 0);
          }
        }
      #pragma unroll
      for (int mt = 0; mt < 2; ++mt)
        #pragma unroll
        for (int ntl = 0; ntl < 2; ++ntl) {
          x0f[mt][p].u[2 * ntl + 0] = cvtpk(acc[ntl][mt][0], acc[ntl][mt][1]);
          x0f[mt][p].u[2 * ntl + 1] = cvtpk(acc[ntl][mt][2], acc[ntl][mt][3]);
        }
    }
  };

  // ---- chain layer half: 2 passes from `buf`; hout[.][p] = bf16(relu+x0) --
  auto chain_half = [&](const uint16_t* buf, int p0, const F4* bb,
                        Frag (&hin)[2][4], Frag (&hout)[2][4]) {
    #pragma unroll
    for (int pp = 0; pp < 2; ++pp) {
      const int p = p0 + pp;
      f32x4 acc[2][2];
      #pragma unroll
      for (int kt = 0; kt < 4; ++kt)
        #pragma unroll
        for (int ntl = 0; ntl < 2; ++ntl) {
          const int ntloc = 2 * pp + ntl;
          Frag wf;
          wf.v = *reinterpret_cast<const bs8*>(buf + ((ntloc * 4 + kt) * 64 + lane) * 8);
          #pragma unroll
          for (int mt = 0; mt < 2; ++mt) {
            f32x4 c = (kt == 0) ? bb[2 * p + ntl].v : acc[ntl][mt];
            acc[ntl][mt] = __builtin_amdgcn_mfma_f32_16x16x32_bf16(wf.v, hin[mt][kt].v, c, 0, 0, 0);
          }
        }
      #pragma unroll
      for (int mt = 0; mt < 2; ++mt)
        #pragma unroll
        for (int ntl = 0; ntl < 2; ++ntl) {
          f32x4 r = __builtin_elementwise_max(acc[ntl][mt], zero4);
          uint32_t xw0 = x0f[mt][p].u[2 * ntl + 0];
          uint32_t xw1 = x0f[mt][p].u[2 * ntl + 1];
          f32x4 xv;
          xv[0] = __uint_as_float(xw0 << 16);
          xv[1] = __uint_as_float(xw0 & 0xffff0000u);
          xv[2] = __uint_as_float(xw1 << 16);
          xv[3] = __uint_as_float(xw1 & 0xffff0000u);
          r = r + xv;
          hout[mt][p].u[2 * ntl + 0] = cvtpk(r[0], r[1]);
          hout[mt][p].u[2 * ntl + 1] = cvtpk(r[2], r[3]);
        }
    }
  };

  // ---- start layer (pipelined over its 2 chunks) ----
  F4 barr[8];
  #pragma unroll
  for (int nt = 0; nt < 8; ++nt)
    barr[nt].f = *reinterpret_cast<const float4*>(b_start + nt * 16 + q * 4);

  __syncthreads();                           // X = Wsc0 ready
  stage(Y, wfrag + 8192);                    // Wsc1
  start_half(X, 0, barr);
  __syncthreads();                           // Y ready, X reads done
  const uint16_t* chain = wfrag + 16384;
  stage(X, chain);                           // L0c0
  start_half(Y, 2, barr);
  #pragma unroll
  for (int mt = 0; mt < 2; ++mt)
    #pragma unroll
    for (int kt = 0; kt < 4; ++kt)
      hA[mt][kt].v = x0f[mt][kt].v;          // h = x0

  // ---- 32 layers, 2 chunks each; h ping-pong via 2x unroll ----
  #pragma unroll 1
  for (int l = 0; l < 32; l += 2) {
    // layer l: hA -> hB
    __syncthreads();                         // X = Ll c0 ready
    stage(Y, chain + l * 16384 + 8192);      // Ll c1
    {
      const float* bl = layer_b + l * 128;
      #pragma unroll
      for (int nt = 0; nt < 8; ++nt)
        barr[nt].f = *reinterpret_cast<const float4*>(bl + nt * 16 + q * 4);
    }
    chain_half(X, 0, barr, hA, hB);
    __syncthreads();                         // Y ready, X reads done
    stage(X, chain + (l + 1) * 16384);       // L(l+1) c0
    chain_half(Y, 2, barr, hA, hB);

    // layer l+1: hB -> hA
    __syncthreads();                         // X = L(l+1) c0 ready
    stage(Y, chain + (l + 1) * 16384 + 8192);// L(l+1) c1
    {
      const float* bl = layer_b + (l + 1) * 128;
      #pragma unroll
      for (int nt = 0; nt < 8; ++nt)
        barr[nt].f = *reinterpret_cast<const float4*>(bl + nt * 16 + q * 4);
    }
    chain_half(X, 0, barr, hB, hA);
    __syncthreads();                         // Y ready, X reads done
    if (l + 2 < 32) stage(X, chain + (l + 2) * 16384);
    chain_half(Y, 2, barr, hB, hA);
  }
  __syncthreads();                           // all chain compute done; LDS free

  // ---- output layer: logits^T = Wo * h^T + bo (W_out from global, L2) ----
  const uint16_t* wout = wfrag + 540672;
  F4 bo[4];
  #pragma unroll
  for (int nt = 0; nt < 4; ++nt)
    bo[nt].f = *reinterpret_cast<const float4*>(b_out + nt * 16 + q * 4);
  f32x4 ao[4][2];  // [nt][mt]
  #pragma unroll
  for (int kt = 0; kt < 4; ++kt) {
    #pragma unroll
    for (int nt = 0; nt < 4; ++nt) {
      Frag wf;
      wf.v = *reinterpret_cast<const bs8*>(wout + ((nt * 4 + kt) * 64 + lane) * 8);
      #pragma unroll
      for (int mt = 0; mt < 2; ++mt) {
        f32x4 c = (kt == 0) ? bo[nt].v : ao[nt][mt];
        ao[nt][mt] = __builtin_amdgcn_mfma_f32_16x16x32_bf16(wf.v, hA[mt][kt].v, c, 0, 0, 0);
      }
    }
  }

  // ---- softmax over 64 classes + transposed store via LDS scratch ----
  float* tr = reinterpret_cast<float*>(lds) + wave * 1088;   // 16x68 floats
  #pragma unroll
  for (int mt = 0; mt < 2; ++mt) {
    float e[16];
    float M = -3.0e38f;
    #pragma unroll
    for (int nt = 0; nt < 4; ++nt)
      #pragma unroll
      for (int r = 0; r < 4; ++r)
        M = fmaxf(M, ao[nt][mt][r]);
    M = fmaxf(M, __shfl_xor(M, 16, 64));
    M = fmaxf(M, __shfl_xor(M, 32, 64));
    float S = 0.0f;
    #pragma unroll
    for (int nt = 0; nt < 4; ++nt)
      #pragma unroll
      for (int r = 0; r < 4; ++r) {
        float t = exp2f((ao[nt][mt][r] - M) * 1.4426950408889634f);
        e[nt * 4 + r] = t;
        S += t;
      }
    S += __shfl_xor(S, 16, 64);
    S += __shfl_xor(S, 32, 64);
    const float inv = 1.0f / S;
    #pragma unroll
    for (int nt = 0; nt < 4; ++nt) {
      float4 pv;
      pv.x = e[nt * 4 + 0] * inv;
      pv.y = e[nt * 4 + 1] * inv;
      pv.z = e[nt * 4 + 2] * inv;
      pv.w = e[nt * 4 + 3] * inv;
      *reinterpret_cast<float4*>(tr + mc * 68 + nt * 16 + q * 4) = pv;
    }
    __asm__ volatile("s_waitcnt lgkmcnt(0)" ::: "memory");
    #pragma unroll
    for (int it = 0; it < 4; ++it) {
      int row = it * 4 + (lane >> 4);
      float4 v = *reinterpret_cast<const float4*>(tr + row * 68 + (lane & 15) * 4);
      long gr = batch0 + mt * 16 + row;
      *reinterpret_cast<float4*>(out + gr * 64 + (lane & 15) * 4) = v;
    }
    __asm__ volatile("s_waitcnt lgkmcnt(0)" ::: "memory");
  }
}

// ---------------------------------------------------------------------------
extern "C" void kernel_launch(void* const* d_in, const int* in_sizes, int n_in,
                              void* d_out, int out_size, void* d_ws, size_t ws_size,
                              hipStream_t stream) {
  const float* x        = (const float*)d_in[0];
  const float* w_start  = (const float*)d_in[1];
  const float* b_start  = (const float*)d_in[2];
  const float* masked_w = (const float*)d_in[3];
  const float* layer_b  = (const float*)d_in[4];
  const float* w_out    = (const float*)d_in[5];
  const float* b_out    = (const float*)d_in[6];
  uint16_t* wfrag = (uint16_t*)d_ws;   // 1,097,728 B < ws_size

  prep_frags<<<268, 256, 0, stream>>>(w_start, masked_w, w_out, wfrag);
  wann_main<<<1024, 256, 32768, stream>>>(x, b_start, layer_b, b_out, wfrag,
                                          (float*)d_out);
}